// Round 1
// baseline (558.569 us; speedup 1.0000x reference)
//
#include <hip/hip_runtime.h>

#define HW 65536
#define CDIM 512
#define NN 50
#define NROWS 51

__device__ __forceinline__ float wave_sum(float v) {
#pragma unroll
  for (int off = 32; off; off >>= 1) v += __shfl_xor(v, off, 64);
  return v;
}
__device__ __forceinline__ int wave_sum_i(int v) {
#pragma unroll
  for (int off = 32; off; off >>= 1) v += __shfl_xor(v, off, 64);
  return v;
}
__device__ __forceinline__ float wave_max(float v) {
#pragma unroll
  for (int off = 32; off; off >>= 1) v = fmaxf(v, __shfl_xor(v, off, 64));
  return v;
}

// ---------------- T0: transpose the 6 weight matrices --------------------
__global__ __launch_bounds__(256) void k_transpose(
    const float* g0, const float* g1, const float* qw, const float* kw,
    const float* vw, const float* mw,
    float* g0T, float* g1T, float* qwT, float* kwT, float* vwT, float* mwT) {
  const float* in; float* out; int rows, cols;
  switch (blockIdx.z) {
    case 0: in = g0; out = g0T; rows = 512; cols = 512; break;
    case 1: in = g1; out = g1T; rows = 512; cols = 512; break;
    case 2: in = qw; out = qwT; rows = 256; cols = 512; break;
    case 3: in = kw; out = kwT; rows = 256; cols = 512; break;
    case 4: in = vw; out = vwT; rows = 512; cols = 512; break;
    default: in = mw; out = mwT; rows = 512; cols = 512; break;
  }
  int c0 = blockIdx.x * 32, r0 = blockIdx.y * 32;
  if (r0 >= rows || c0 >= cols) return;
  __shared__ float tile[32][33];
  int tx = threadIdx.x, ty = threadIdx.y;
#pragma unroll
  for (int j = 0; j < 4; ++j)
    tile[ty + j * 8][tx] = in[(size_t)(r0 + ty + j * 8) * cols + c0 + tx];
  __syncthreads();
#pragma unroll
  for (int j = 0; j < 4; ++j)
    out[(size_t)(c0 + ty + j * 8) * rows + r0 + tx] = tile[tx][ty + j * 8];
}

// ---------------- S1: per-1024px block fg counts + zero seg --------------
__global__ __launch_bounds__(256) void k_count(const int* msk, int* blkcnt, float* seg) {
  int t = threadIdx.x, b = blockIdx.x;
  int g = b * 256 + t;
  if (g < NN * CDIM) seg[g] = 0.f;
  int g2 = g + 16384;
  if (g2 < NN * CDIM) seg[g2] = 0.f;
  int4 m = ((const int4*)msk)[g];
  int c = (m.x != 0) + (m.y != 0) + (m.z != 0) + (m.w != 0);
  c = wave_sum_i(c);
  __shared__ int wl[4];
  if ((t & 63) == 0) wl[t >> 6] = c;
  __syncthreads();
  if (t == 0) blkcnt[b] = wl[0] + wl[1] + wl[2] + wl[3];
}

// ---------------- S2: scan blkcnt (64) + bin metadata --------------------
__global__ void k_scan(const int* blkcnt, int* blkoff, int* meta) {
  int t = threadIdx.x;  // 64 threads, 1 wave
  int c = blkcnt[t];
  int x = c;
#pragma unroll
  for (int d = 1; d < 64; d <<= 1) {
    int y = __shfl_up(x, d, 64);
    if (t >= d) x += y;
  }
  blkoff[t] = x - c;
  int L = __shfl(x, 63, 64);
  if (t == 0) meta[0] = L;
  if (t < NN) {
    long long Ll = L;
    int s = (int)((long long)t * Ll / NN);
    int e = (int)(((long long)(t + 1) * Ll + NN - 1) / NN);
    int sn = (int)((long long)(t + 1) * Ll / NN);
    meta[2 + t] = s;                               // starts
    meta[2 + NN + t] = e - s;                      // cnt
    meta[2 + 2 * NN + t] = (t < NN - 1) ? (e > sn) : 0;  // overlap flag
  }
}

// ---------------- S2b: per-pixel rank -> bin8; boundary pixels P ---------
__global__ __launch_bounds__(256) void k_rank(const int* msk, const int* blkoff,
                                              const int* meta, unsigned char* bin8, int* P) {
  int t = threadIdx.x, blk = blockIdx.x;
  int L = meta[0];
  __shared__ int sst[NN];
  __shared__ int wtot[4];
  if (t < NN) sst[t] = meta[2 + t];
  int4 m = ((const int4*)msk)[blk * 256 + t];
  int fl[4] = {m.x != 0, m.y != 0, m.z != 0, m.w != 0};
  int cnt = fl[0] + fl[1] + fl[2] + fl[3];
  int lane = t & 63, wv = t >> 6;
  int x = cnt;
#pragma unroll
  for (int d = 1; d < 64; d <<= 1) {
    int y = __shfl_up(x, d, 64);
    if (lane >= d) x += y;
  }
  if (lane == 63) wtot[wv] = x;
  __syncthreads();
  int base = blkoff[blk] + (x - cnt);
  for (int w = 0; w < wv; ++w) base += wtot[w];
  int p0 = blk * 1024 + t * 4;
  int r = base;
#pragma unroll
  for (int j = 0; j < 4; ++j) {
    int p = p0 + j;
    unsigned char bv = 255;
    if (fl[j]) {
      bv = (unsigned char)((long long)NN * r / L);
#pragma unroll 1
      for (int i = 0; i < NN; ++i)
        if (sst[i] == r) P[i] = p;
      r++;
    }
    bin8[p] = bv;
  }
}

// ---------------- S3: THE heavy pass — segment sums ----------------------
__global__ __launch_bounds__(256) void k_seg(const float* __restrict__ fts,
                                             const unsigned char* __restrict__ bin8,
                                             float* __restrict__ seg) {
  int pb = blockIdx.x * 1024;
  int cwb = blockIdx.y * 64;
  int t = threadIdx.x, lane = t & 63, wv = t >> 6;
  __shared__ int sbm[2];
  if (t == 0) { sbm[0] = 255; sbm[1] = -1; }
  __syncthreads();
  uchar4 b4 = ((const uchar4*)bin8)[(pb >> 2) + t];
  int bb[4] = {b4.x, b4.y, b4.z, b4.w};
  int mn = 255, mx = -1;
#pragma unroll
  for (int j = 0; j < 4; ++j)
    if (bb[j] != 255) { mn = min(mn, bb[j]); mx = max(mx, bb[j]); }
  if (mn < 255) atomicMin(&sbm[0], mn);
  if (mx >= 0) atomicMax(&sbm[1], mx);
  __syncthreads();
  int bmin = sbm[0], bmax = sbm[1];
  if (bmax < 0) return;  // no foreground in this pixel block
  int cw = cwb + wv * 16;
  const float* base = fts + (size_t)cw * HW + pb + lane;
  const unsigned char* bp = bin8 + pb + lane;
  if (bmax - bmin <= 3) {
    float racc[16][4];
#pragma unroll
    for (int a = 0; a < 16; ++a)
#pragma unroll
      for (int j = 0; j < 4; ++j) racc[a][j] = 0.f;
#pragma unroll 1
    for (int it = 0; it < 16; ++it) {
      int b = bp[it * 64];
      int brel = b - bmin;
      bool k0 = brel == 0, k1 = brel == 1, k2 = brel == 2, k3 = brel == 3;
#pragma unroll
      for (int cs = 0; cs < 16; ++cs) {
        float v = base[(size_t)cs * HW + it * 64];
        racc[cs][0] += k0 ? v : 0.f;
        racc[cs][1] += k1 ? v : 0.f;
        racc[cs][2] += k2 ? v : 0.f;
        racc[cs][3] += k3 ? v : 0.f;
      }
    }
#pragma unroll 1
    for (int cs = 0; cs < 16; ++cs) {
#pragma unroll 1
      for (int j = 0; j < 4; ++j) {
        float v = wave_sum(racc[cs][j]);
        if (lane == 0 && v != 0.f) {
          int b = bmin + j;
          if (b < NN) atomicAdd(&seg[b * CDIM + cw + cs], v);
        }
      }
    }
  } else {
    // pathological-L fallback (never taken for this data): direct atomics
    for (int it = 0; it < 16; ++it) {
      int b = bp[it * 64];
      if (b == 255) continue;
      for (int cs = 0; cs < 16; ++cs) {
        float v = base[(size_t)cs * HW + it * 64];
        atomicAdd(&seg[b * CDIM + cw + cs], v);
      }
    }
  }
}

// ---------------- S4: build H (51x512), glob, norms ----------------------
__global__ __launch_bounds__(512) void k_buildH(const float* fts, const float* seg,
                                                const int* meta, const int* P,
                                                float* glob, float* H, float* norms) {
  int r = blockIdx.x;   // 0..50
  int c = threadIdx.x;  // 512
  int L = meta[0];
  float h;
  if (r == 0) {
    float s = 0.f;
#pragma unroll 1
    for (int i = 0; i < NN; ++i) s += seg[i * CDIM + c];
    h = s / ((float)L + 1e-8f);
    glob[c] = h;
  } else {
    int i = r - 1;
    const int* cntv = meta + 2 + NN;
    const int* ov = meta + 2 + 2 * NN;
    float s = seg[i * CDIM + c];
    if (ov[i]) s += fts[(size_t)c * HW + P[i + 1]];
    h = s / fmaxf((float)cntv[i], 1.f);
  }
  H[r * CDIM + c] = h;
  float x = wave_sum(h * h);
  __shared__ float wsum[8];
  if ((c & 63) == 0) wsum[c >> 6] = x;
  __syncthreads();
  if (c == 0) {
    float s = 0.f;
    for (int w = 0; w < 8; ++w) s += wsum[w];
    norms[r] = fmaxf(sqrtf(s), 1e-12f);
  }
}

// ---------------- GCN A: adj row + agg row -------------------------------
__global__ __launch_bounds__(256) void k_gcnA(const float* H, const float* norms, float* agg) {
  int a = blockIdx.x;
  int t = threadIdx.x, lane = t & 63, wv = t >> 6;
  __shared__ float sHa[CDIM];
  __shared__ float sadj[64];
  sHa[t] = H[a * CDIM + t];
  sHa[t + 256] = H[a * CDIM + t + 256];
  __syncthreads();
  float na = norms[a];
  for (int b = wv; b < NROWS; b += 4) {
    float d = 0.f;
#pragma unroll 2
    for (int k = lane; k < CDIM; k += 64) d += sHa[k] * H[b * CDIM + k];
    d = wave_sum(d);
    if (lane == 0) sadj[b] = fmaxf(d / (na * norms[b]), 0.f);
  }
  __syncthreads();
  if (t < 64) {
    float s = (t < NROWS) ? sadj[t] : -1e30f;
    float m = wave_max(s);
    float e = (t < NROWS) ? expf(s - m) : 0.f;
    float sum = wave_sum(e);
    if (t < NROWS) sadj[t] = e / sum;
  }
  __syncthreads();
  for (int c = t; c < CDIM; c += 256) {
    float acc = 0.f;
#pragma unroll 1
    for (int b = 0; b < NROWS; ++b) acc += sadj[b] * H[b * CDIM + c];
    agg[a * CDIM + c] = acc;
  }
}

// ---------------- GCN B: H += relu(agg @ W^T + b); new norms -------------
__global__ __launch_bounds__(512) void k_gcnB(float* H, const float* agg,
                                              const float* WT, const float* bias,
                                              float* norms) {
  int r = blockIdx.x, c = threadIdx.x;
  __shared__ float sagg[CDIM];
  sagg[c] = agg[r * CDIM + c];
  __syncthreads();
  float acc = bias[c];
#pragma unroll 4
  for (int k = 0; k < CDIM; ++k) acc += sagg[k] * WT[k * CDIM + c];
  float h = H[r * CDIM + c] + fmaxf(acc, 0.f);
  H[r * CDIM + c] = h;
  float x = wave_sum(h * h);
  __shared__ float wsum[8];
  if ((c & 63) == 0) wsum[c >> 6] = x;
  __syncthreads();
  if (c == 0) {
    float s = 0.f;
    for (int w = 0; w < 8; ++w) s += wsum[w];
    norms[r] = fmaxf(sqrtf(s), 1e-12f);
  }
}

// ---------------- F1: q, k, v projections --------------------------------
__global__ __launch_bounds__(256) void k_qkv(const float* H, const float* qwT,
                                             const float* kwT, const float* vwT,
                                             const float* qb, const float* kb, const float* vb,
                                             float* q, float* kk, float* vv) {
  int blk = blockIdx.x;  // 0 -> q from H[0]; 1..50 -> k,v from H[blk]
  int t = threadIdx.x;
  __shared__ float sh[CDIM];
  sh[t] = H[blk * CDIM + t];
  sh[t + 256] = H[blk * CDIM + t + 256];
  __syncthreads();
  if (blk == 0) {
    float acc = qb[t];
#pragma unroll 4
    for (int k = 0; k < CDIM; ++k) acc += sh[k] * qwT[k * 256 + t];
    q[t] = acc;
  } else {
    int i = blk - 1;
    float acc = kb[t];
#pragma unroll 4
    for (int k = 0; k < CDIM; ++k) acc += sh[k] * kwT[k * 256 + t];
    kk[i * 256 + t] = acc;
    float a0 = vb[t], a1 = vb[t + 256];
#pragma unroll 4
    for (int k = 0; k < CDIM; ++k) {
      float hv = sh[k];
      a0 += hv * vwT[k * CDIM + t];
      a1 += hv * vwT[k * CDIM + t + 256];
    }
    vv[i * CDIM + t] = a0;
    vv[i * CDIM + t + 256] = a1;
  }
}

// ---------------- F2: attention + map + blend ----------------------------
__global__ __launch_bounds__(512) void k_final(const float* H, const float* glob,
                                               const float* q, const float* kk, const float* vv,
                                               const float* mapwT, const float* mapb,
                                               const float* gamma, const float* alpha,
                                               float* out) {
  int t = threadIdx.x, lane = t & 63, wv = t >> 6;
  __shared__ float sattn[64];
  __shared__ float sav[CDIM];
  for (int i = wv; i < NN; i += 8) {
    float d = 0.f;
#pragma unroll
    for (int k = lane; k < 256; k += 64) d += q[k] * kk[i * 256 + k];
    d = wave_sum(d);
    if (lane == 0) sattn[i] = d * (1.f / 16.f);
  }
  __syncthreads();
  if (t < 64) {
    float s = (t < NN) ? sattn[t] : -1e30f;
    float m = wave_max(s);
    float e = (t < NN) ? expf(s - m) : 0.f;
    float sum = wave_sum(e);
    if (t < NN) sattn[t] = e / sum;
  }
  __syncthreads();
  float av = 0.f;
#pragma unroll 1
  for (int i = 0; i < NN; ++i) av += sattn[i] * vv[i * CDIM + t];
  sav[t] = av;
  __syncthreads();
  float o = mapb[t];
#pragma unroll 4
  for (int k = 0; k < CDIM; ++k) o += sav[k] * mapwT[k * CDIM + t];
  float w = 1.f / (1.f + expf(-alpha[0]));
  float fp = H[t] + gamma[0] * o;  // H row 0 == q_node
  out[t] = glob[t] * (1.f - w) + fp * w;
}

// -------------------------------------------------------------------------
extern "C" void kernel_launch(void* const* d_in, const int* in_sizes, int n_in,
                              void* d_out, int out_size, void* d_ws, size_t ws_size,
                              hipStream_t stream) {
  const float* fts = (const float*)d_in[0];
  const int* msk = (const int*)d_in[1];
  const float* gcn_w = (const float*)d_in[2];
  const float* gcn_b = (const float*)d_in[3];
  const float* q_w = (const float*)d_in[4];
  const float* q_b = (const float*)d_in[5];
  const float* k_w = (const float*)d_in[6];
  const float* k_b = (const float*)d_in[7];
  const float* v_w = (const float*)d_in[8];
  const float* v_b = (const float*)d_in[9];
  const float* map_w = (const float*)d_in[10];
  const float* map_b = (const float*)d_in[11];
  const float* gamma = (const float*)d_in[12];
  const float* alpha = (const float*)d_in[13];
  float* out = (float*)d_out;

  char* w = (char*)d_ws;
  auto alloc = [&](size_t bytes) {
    char* p = w;
    w += (bytes + 255) & ~(size_t)255;
    return p;
  };
  float* g0T = (float*)alloc(512 * 512 * 4);
  float* g1T = (float*)alloc(512 * 512 * 4);
  float* qwT = (float*)alloc(512 * 256 * 4);
  float* kwT = (float*)alloc(512 * 256 * 4);
  float* vwT = (float*)alloc(512 * 512 * 4);
  float* mwT = (float*)alloc(512 * 512 * 4);
  int* blkcnt = (int*)alloc(64 * 4);
  int* blkoff = (int*)alloc(64 * 4);
  int* meta = (int*)alloc(160 * 4);
  int* P = (int*)alloc(NN * 4);
  unsigned char* bin8 = (unsigned char*)alloc(HW);
  float* seg = (float*)alloc(NN * CDIM * 4);
  float* glob = (float*)alloc(CDIM * 4);
  float* H = (float*)alloc(NROWS * CDIM * 4);
  float* norms = (float*)alloc(NROWS * 4);
  float* agg = (float*)alloc(NROWS * CDIM * 4);
  float* qv = (float*)alloc(256 * 4);
  float* kv = (float*)alloc(NN * 256 * 4);
  float* vv = (float*)alloc(NN * CDIM * 4);

  k_transpose<<<dim3(16, 16, 6), dim3(32, 8), 0, stream>>>(
      gcn_w, gcn_w + 512 * 512, q_w, k_w, v_w, map_w, g0T, g1T, qwT, kwT, vwT, mwT);
  k_count<<<64, 256, 0, stream>>>(msk, blkcnt, seg);
  k_scan<<<1, 64, 0, stream>>>(blkcnt, blkoff, meta);
  k_rank<<<64, 256, 0, stream>>>(msk, blkoff, meta, bin8, P);
  k_seg<<<dim3(64, 8), 256, 0, stream>>>(fts, bin8, seg);
  k_buildH<<<NROWS, 512, 0, stream>>>(fts, seg, meta, P, glob, H, norms);
  for (int l = 0; l < 2; ++l) {
    k_gcnA<<<NROWS, 256, 0, stream>>>(H, norms, agg);
    k_gcnB<<<NROWS, 512, 0, stream>>>(H, agg, l ? g1T : g0T, gcn_b + l * 512, norms);
  }
  k_qkv<<<NROWS, 256, 0, stream>>>(H, qwT, kwT, vwT, q_b, k_b, v_b, qv, kv, vv);
  k_final<<<1, 512, 0, stream>>>(H, glob, qv, kv, vv, mwT, map_b, gamma, alpha, out);
}

// Round 2
// 454.198 us; speedup vs baseline: 1.2298x; 1.2298x over previous
//
#include <hip/hip_runtime.h>

#define HW 65536
#define CDIM 512
#define NN 50
#define NROWS 51

__device__ __forceinline__ float wave_sum(float v) {
#pragma unroll
  for (int off = 32; off; off >>= 1) v += __shfl_xor(v, off, 64);
  return v;
}
__device__ __forceinline__ int wave_sum_i(int v) {
#pragma unroll
  for (int off = 32; off; off >>= 1) v += __shfl_xor(v, off, 64);
  return v;
}
__device__ __forceinline__ float wave_max(float v) {
#pragma unroll
  for (int off = 32; off; off >>= 1) v = fmaxf(v, __shfl_xor(v, off, 64));
  return v;
}
__device__ __forceinline__ int wave_max_i(int v) {
#pragma unroll
  for (int off = 32; off; off >>= 1) v = max(v, __shfl_xor(v, off, 64));
  return v;
}
__device__ __forceinline__ int wave_min_i(int v) {
#pragma unroll
  for (int off = 32; off; off >>= 1) v = min(v, __shfl_xor(v, off, 64));
  return v;
}

// ---- P0: fused mask-count + seg/nsq zero + 6 weight transposes ----------
// blocks 0..63: count fg per 1024-px block, zero seg/nsq
// blocks 64..1343: 32x32 transpose tiles of the 6 weight matrices
__global__ __launch_bounds__(256) void k_prep(
    const int* __restrict__ msk, int* __restrict__ blkcnt, float* __restrict__ seg,
    float* __restrict__ nsqB, float* __restrict__ nsqC,
    const float* __restrict__ g0, const float* __restrict__ g1,
    const float* __restrict__ qw, const float* __restrict__ kw,
    const float* __restrict__ vw, const float* __restrict__ mw,
    float* __restrict__ g0T, float* __restrict__ g1T, float* __restrict__ qwT,
    float* __restrict__ kwT, float* __restrict__ vwT, float* __restrict__ mwT) {
  int t = threadIdx.x, b = blockIdx.x;
  __shared__ float tile[32][33];
  __shared__ int wl[4];
  if (b < 64) {
    int g = b * 256 + t;
    if (g < NN * CDIM) seg[g] = 0.f;
    int g2 = g + 16384;
    if (g2 < NN * CDIM) seg[g2] = 0.f;
    if (b == 0 && t < NROWS) { nsqB[t] = 0.f; nsqC[t] = 0.f; }
    int4 m = ((const int4*)msk)[g];
    int c = (m.x != 0) + (m.y != 0) + (m.z != 0) + (m.w != 0);
    c = wave_sum_i(c);
    if ((t & 63) == 0) wl[t >> 6] = c;
    __syncthreads();
    if (t == 0) blkcnt[b] = wl[0] + wl[1] + wl[2] + wl[3];
  } else {
    int tid = b - 64;
    const float* in; float* out; int rows, cols, lt;
    if (tid < 256)       { in = g0; out = g0T; rows = 512; cols = 512; lt = tid; }
    else if (tid < 512)  { in = g1; out = g1T; rows = 512; cols = 512; lt = tid - 256; }
    else if (tid < 640)  { in = qw; out = qwT; rows = 256; cols = 512; lt = tid - 512; }
    else if (tid < 768)  { in = kw; out = kwT; rows = 256; cols = 512; lt = tid - 640; }
    else if (tid < 1024) { in = vw; out = vwT; rows = 512; cols = 512; lt = tid - 768; }
    else                 { in = mw; out = mwT; rows = 512; cols = 512; lt = tid - 1024; }
    int ctiles = cols / 32;
    int r0 = (lt / ctiles) * 32, c0 = (lt % ctiles) * 32;
    int tx = t & 31, ty = t >> 5;
#pragma unroll
    for (int j = 0; j < 4; ++j)
      tile[ty + j * 8][tx] = in[(size_t)(r0 + ty + j * 8) * cols + c0 + tx];
    __syncthreads();
#pragma unroll
    for (int j = 0; j < 4; ++j)
      out[(size_t)(c0 + ty + j * 8) * rows + r0 + tx] = tile[tx][ty + j * 8];
  }
}

// ---- P1: per-block scan (redundant per block, 64 values) + ranks --------
// meta layout: [0]=L, [2..51]=starts, [52..101]=cnt, [102..151]=ovs
__global__ __launch_bounds__(256) void k_rank(const int* __restrict__ msk,
                                              const int* __restrict__ blkcnt,
                                              int* __restrict__ meta,
                                              unsigned char* __restrict__ bin8,
                                              int* __restrict__ P) {
  int t = threadIdx.x, blk = blockIdx.x;
  __shared__ int sblkoff, sL;
  __shared__ int sst[NN + 1];
  __shared__ int wtot[4];
  if (t < 64) {
    int c = blkcnt[t];
    int x = c;
#pragma unroll
    for (int d = 1; d < 64; d <<= 1) {
      int y = __shfl_up(x, d, 64);
      if (t >= d) x += y;
    }
    if (t == blk) sblkoff = x - c;
    if (t == 63) sL = x;
  }
  __syncthreads();
  int L = sL;
  if (t <= NN) sst[t] = (int)((long long)t * L / NN);
  if (blk == 0 && t < NN) {
    if (t == 0) meta[0] = L;
    long long Ll = L;
    int s = (int)((long long)t * Ll / NN);
    int e = (int)(((long long)(t + 1) * Ll + NN - 1) / NN);
    int ci = (int)(((long long)t * Ll + NN - 1) / NN);  // ceil(tL/NN)
    meta[2 + NN + t] = e - s;                            // cnt
    meta[2 + 2 * NN + t] = (t >= 1 && ci > s) ? 1 : 0;   // extra-pixel flag (rank s_t)
  }
  int4 m = ((const int4*)msk)[blk * 256 + t];
  int fl[4] = {m.x != 0, m.y != 0, m.z != 0, m.w != 0};
  int cnt = fl[0] + fl[1] + fl[2] + fl[3];
  int lane = t & 63, wv = t >> 6;
  int x = cnt;
#pragma unroll
  for (int d = 1; d < 64; d <<= 1) {
    int y = __shfl_up(x, d, 64);
    if (lane >= d) x += y;
  }
  if (lane == 63) wtot[wv] = x;
  __syncthreads();
  int base = sblkoff + (x - cnt);
  for (int w = 0; w < wv; ++w) base += wtot[w];
  int p0 = blk * 1024 + t * 4;
  int r = base;
#pragma unroll
  for (int j = 0; j < 4; ++j) {
    int p = p0 + j;
    unsigned char bv = 255;
    if (fl[j]) {
      int bi = (int)((long long)NN * r / L);
      bv = (unsigned char)bi;
      if (sst[bi] == r) P[bi] = p;
      if (bi + 1 < NN && sst[bi + 1] == r) P[bi + 1] = p;
      r++;
    }
    bin8[p] = bv;
  }
}

// ---- P2: heavy pass — floor-bucket segment sums over fts ----------------
__global__ __launch_bounds__(256) void k_seg(const float* __restrict__ fts,
                                             const unsigned char* __restrict__ bin8,
                                             float* __restrict__ seg) {
  int pb = blockIdx.x * 256;
  int t = threadIdx.x, lane = t & 63, wv = t >> 6;
  int cw = blockIdx.y * 64 + wv * 16;
  uchar4 b4 = *(const uchar4*)(bin8 + pb + lane * 4);
  int bb[4] = {b4.x, b4.y, b4.z, b4.w};
  int mn = 255, mx = -1;
#pragma unroll
  for (int j = 0; j < 4; ++j)
    if (bb[j] != 255) { mn = min(mn, bb[j]); mx = max(mx, bb[j]); }
  mn = wave_min_i(mn);
  mx = wave_max_i(mx);
  if (mx < 0) return;  // all-background window
  const float* base = fts + (size_t)cw * HW + pb + lane * 4;
  int span = mx - mn;
  if (span <= 3) {
    int br0 = bb[0] - mn, br1 = bb[1] - mn, br2 = bb[2] - mn, br3 = bb[3] - mn;
    float racc[16][4];
#pragma unroll
    for (int a = 0; a < 16; ++a)
#pragma unroll
      for (int j = 0; j < 4; ++j) racc[a][j] = 0.f;
#pragma unroll 8
    for (int cs = 0; cs < 16; ++cs) {
      float4 v = *(const float4*)(base + (size_t)cs * HW);
      racc[cs][0] += (br0 == 0 ? v.x : 0.f) + (br1 == 0 ? v.y : 0.f) +
                     (br2 == 0 ? v.z : 0.f) + (br3 == 0 ? v.w : 0.f);
      racc[cs][1] += (br0 == 1 ? v.x : 0.f) + (br1 == 1 ? v.y : 0.f) +
                     (br2 == 1 ? v.z : 0.f) + (br3 == 1 ? v.w : 0.f);
      racc[cs][2] += (br0 == 2 ? v.x : 0.f) + (br1 == 2 ? v.y : 0.f) +
                     (br2 == 2 ? v.z : 0.f) + (br3 == 2 ? v.w : 0.f);
      racc[cs][3] += (br0 == 3 ? v.x : 0.f) + (br1 == 3 ? v.y : 0.f) +
                     (br2 == 3 ? v.z : 0.f) + (br3 == 3 ? v.w : 0.f);
    }
#pragma unroll 1
    for (int cs = 0; cs < 16; ++cs) {
#pragma unroll
      for (int j = 0; j < 4; ++j) {
        if (j <= span) {
          float s = wave_sum(racc[cs][j]);
          if (lane == 0 && s != 0.f) atomicAdd(&seg[(mn + j) * CDIM + cw + cs], s);
        }
      }
    }
  } else {
    // pathological fallback (span > 3): per-pixel atomics, correct but slow
#pragma unroll 1
    for (int cs = 0; cs < 16; ++cs) {
      float4 v = *(const float4*)(base + (size_t)cs * HW);
      float vs[4] = {v.x, v.y, v.z, v.w};
#pragma unroll
      for (int j = 0; j < 4; ++j)
        if (bb[j] != 255) atomicAdd(&seg[bb[j] * CDIM + cw + cs], vs[j]);
    }
  }
}

// ---- P3: build H (51x512), glob, normSq ---------------------------------
__global__ __launch_bounds__(512) void k_buildH(const float* __restrict__ fts,
                                                const float* __restrict__ seg,
                                                const int* __restrict__ meta,
                                                const int* __restrict__ P,
                                                float* __restrict__ glob,
                                                float* __restrict__ H,
                                                float* __restrict__ nsq) {
  int r = blockIdx.x, c = threadIdx.x;
  int L = meta[0];
  float h;
  if (r == 0) {
    float s = 0.f;
#pragma unroll 5
    for (int i = 0; i < NN; ++i) s += seg[i * CDIM + c];
    h = s / ((float)L + 1e-8f);
    glob[c] = h;
  } else {
    int i = r - 1;
    float s = seg[i * CDIM + c];
    if (meta[2 + 2 * NN + i]) s += fts[(size_t)c * HW + P[i]];
    h = s / fmaxf((float)meta[2 + NN + i], 1.f);
  }
  H[r * CDIM + c] = h;
  float x = wave_sum(h * h);
  __shared__ float wsum[8];
  if ((c & 63) == 0) wsum[c >> 6] = x;
  __syncthreads();
  if (c == 0) {
    float s = 0.f;
#pragma unroll
    for (int w = 0; w < 8; ++w) s += wsum[w];
    nsq[r] = s;
  }
}

// ---- P4: fused GCN layer (adj+softmax+agg duplicated per c-split) -------
__global__ __launch_bounds__(128) void k_gcn(const float* __restrict__ Hin,
                                             const float* __restrict__ nsqIn,
                                             float* __restrict__ Hout,
                                             float* __restrict__ nsqOut,
                                             const float* __restrict__ WT,
                                             const float* __restrict__ bias) {
  int a = blockIdx.x, s = blockIdx.y;
  int t = threadIdx.x, lane = t & 63, w = t >> 6;
  __shared__ float sHa[CDIM];
  __shared__ float sadj[64];
  __shared__ float sagg[CDIM];
#pragma unroll
  for (int i = 0; i < 4; ++i) sHa[t + i * 128] = Hin[a * CDIM + t + i * 128];
  __syncthreads();
  float na = fmaxf(sqrtf(nsqIn[a]), 1e-12f);
  for (int b = w; b < NROWS; b += 2) {
    float d = 0.f;
    const float* hb = Hin + b * CDIM;
#pragma unroll
    for (int k = 0; k < 8; ++k) d += sHa[lane + k * 64] * hb[lane + k * 64];
    d = wave_sum(d);
    if (lane == 0) {
      float nb = fmaxf(sqrtf(nsqIn[b]), 1e-12f);
      sadj[b] = fmaxf(d / (na * nb), 0.f);
    }
  }
  __syncthreads();
  if (t < 64) {
    float sv = (t < NROWS) ? sadj[t] : -1e30f;
    float m = wave_max(sv);
    float e = (t < NROWS) ? expf(sv - m) : 0.f;
    float sum = wave_sum(e);
    if (t < NROWS) sadj[t] = e / sum;
  }
  __syncthreads();
#pragma unroll
  for (int ci = 0; ci < 4; ++ci) {
    int c = t + ci * 128;
    float acc = 0.f;
#pragma unroll 3
    for (int b = 0; b < NROWS; ++b) acc += sadj[b] * Hin[b * CDIM + c];
    sagg[c] = acc;
  }
  __syncthreads();
  int c = s * 128 + t;
  float acc = bias[c];
#pragma unroll 16
  for (int k = 0; k < CDIM; ++k) acc += sagg[k] * WT[k * CDIM + c];
  float h = sHa[c] + fmaxf(acc, 0.f);
  Hout[a * CDIM + c] = h;
  float p = wave_sum(h * h);
  if (lane == 0) atomicAdd(&nsqOut[a], p);
}

// ---- P5: q,k,v projections (c-split over blockIdx.y) --------------------
__global__ __launch_bounds__(128) void k_qkv(const float* __restrict__ H,
                                             const float* __restrict__ qwT,
                                             const float* __restrict__ kwT,
                                             const float* __restrict__ vwT,
                                             const float* __restrict__ qb,
                                             const float* __restrict__ kb,
                                             const float* __restrict__ vb,
                                             float* __restrict__ q,
                                             float* __restrict__ kk,
                                             float* __restrict__ vv) {
  int a = blockIdx.x, s = blockIdx.y, t = threadIdx.x;
  __shared__ float sh[CDIM];
#pragma unroll
  for (int i = 0; i < 4; ++i) sh[t + i * 128] = H[a * CDIM + t + i * 128];
  __syncthreads();
  if (a == 0) {
    if (t < 64) {
      int c = s * 64 + t;
      float acc = qb[c];
#pragma unroll 16
      for (int k = 0; k < CDIM; ++k) acc += sh[k] * qwT[k * 256 + c];
      q[c] = acc;
    }
  } else {
    int i = a - 1;
    if (t < 64) {
      int c = s * 64 + t;
      float acc = kb[c];
#pragma unroll 16
      for (int k = 0; k < CDIM; ++k) acc += sh[k] * kwT[k * 256 + c];
      kk[i * 256 + c] = acc;
    }
    int c = s * 128 + t;
    float acc = vb[c];
#pragma unroll 16
    for (int k = 0; k < CDIM; ++k) acc += sh[k] * vwT[k * CDIM + c];
    vv[i * CDIM + c] = acc;
  }
}

// ---- P6: attention + map matvec (c-split) + blend -----------------------
__global__ __launch_bounds__(128) void k_final(const float* __restrict__ H,
                                               const float* __restrict__ glob,
                                               const float* __restrict__ q,
                                               const float* __restrict__ kk,
                                               const float* __restrict__ vv,
                                               const float* __restrict__ mwT,
                                               const float* __restrict__ mapb,
                                               const float* __restrict__ gamma,
                                               const float* __restrict__ alpha,
                                               float* __restrict__ out) {
  int t = threadIdx.x, lane = t & 63, w = t >> 6;
  __shared__ float sattn[64];
  __shared__ float sav[CDIM];
  for (int i = w; i < NN; i += 2) {
    float d = 0.f;
#pragma unroll
    for (int k = 0; k < 4; ++k) d += q[lane + k * 64] * kk[i * 256 + lane + k * 64];
    d = wave_sum(d);
    if (lane == 0) sattn[i] = d * (1.f / 16.f);
  }
  __syncthreads();
  if (t < 64) {
    float sv = (t < NN) ? sattn[t] : -1e30f;
    float m = wave_max(sv);
    float e = (t < NN) ? expf(sv - m) : 0.f;
    float sum = wave_sum(e);
    if (t < NN) sattn[t] = e / sum;
  }
  __syncthreads();
#pragma unroll
  for (int ci = 0; ci < 4; ++ci) {
    int c = t + ci * 128;
    float acc = 0.f;
#pragma unroll 5
    for (int i = 0; i < NN; ++i) acc += sattn[i] * vv[i * CDIM + c];
    sav[c] = acc;
  }
  __syncthreads();
  int c = blockIdx.x * 128 + t;
  float o = mapb[c];
#pragma unroll 16
  for (int k = 0; k < CDIM; ++k) o += sav[k] * mwT[k * CDIM + c];
  float wv_ = 1.f / (1.f + expf(-alpha[0]));
  float fp = H[c] + gamma[0] * o;  // H row 0 == q_node
  out[c] = glob[c] * (1.f - wv_) + fp * wv_;
}

// -------------------------------------------------------------------------
extern "C" void kernel_launch(void* const* d_in, const int* in_sizes, int n_in,
                              void* d_out, int out_size, void* d_ws, size_t ws_size,
                              hipStream_t stream) {
  const float* fts = (const float*)d_in[0];
  const int* msk = (const int*)d_in[1];
  const float* gcn_w = (const float*)d_in[2];
  const float* gcn_b = (const float*)d_in[3];
  const float* q_w = (const float*)d_in[4];
  const float* q_b = (const float*)d_in[5];
  const float* k_w = (const float*)d_in[6];
  const float* k_b = (const float*)d_in[7];
  const float* v_w = (const float*)d_in[8];
  const float* v_b = (const float*)d_in[9];
  const float* map_w = (const float*)d_in[10];
  const float* map_b = (const float*)d_in[11];
  const float* gamma = (const float*)d_in[12];
  const float* alpha = (const float*)d_in[13];
  float* out = (float*)d_out;

  char* wp = (char*)d_ws;
  auto alloc = [&](size_t bytes) {
    char* p = wp;
    wp += (bytes + 255) & ~(size_t)255;
    return p;
  };
  float* g0T = (float*)alloc(512 * 512 * 4);
  float* g1T = (float*)alloc(512 * 512 * 4);
  float* qwT = (float*)alloc(512 * 256 * 4);
  float* kwT = (float*)alloc(512 * 256 * 4);
  float* vwT = (float*)alloc(512 * 512 * 4);
  float* mwT = (float*)alloc(512 * 512 * 4);
  int* blkcnt = (int*)alloc(64 * 4);
  int* meta = (int*)alloc(160 * 4);
  int* P = (int*)alloc(NN * 4);
  unsigned char* bin8 = (unsigned char*)alloc(HW);
  float* seg = (float*)alloc(NN * CDIM * 4);
  float* glob = (float*)alloc(CDIM * 4);
  float* HA = (float*)alloc(NROWS * CDIM * 4);
  float* HB = (float*)alloc(NROWS * CDIM * 4);
  float* HC = (float*)alloc(NROWS * CDIM * 4);
  float* nsqA = (float*)alloc(NROWS * 4);
  float* nsqB = (float*)alloc(NROWS * 4);
  float* nsqC = (float*)alloc(NROWS * 4);
  float* qv = (float*)alloc(256 * 4);
  float* kv = (float*)alloc(NN * 256 * 4);
  float* vv = (float*)alloc(NN * CDIM * 4);

  k_prep<<<1344, 256, 0, stream>>>(msk, blkcnt, seg, nsqB, nsqC,
                                   gcn_w, gcn_w + 512 * 512, q_w, k_w, v_w, map_w,
                                   g0T, g1T, qwT, kwT, vwT, mwT);
  k_rank<<<64, 256, 0, stream>>>(msk, blkcnt, meta, bin8, P);
  k_seg<<<dim3(256, 8), 256, 0, stream>>>(fts, bin8, seg);
  k_buildH<<<NROWS, 512, 0, stream>>>(fts, seg, meta, P, glob, HA, nsqA);
  k_gcn<<<dim3(NROWS, 4), 128, 0, stream>>>(HA, nsqA, HB, nsqB, g0T, gcn_b);
  k_gcn<<<dim3(NROWS, 4), 128, 0, stream>>>(HB, nsqB, HC, nsqC, g1T, gcn_b + 512);
  k_qkv<<<dim3(NROWS, 4), 128, 0, stream>>>(HC, qwT, kwT, vwT, q_b, k_b, v_b, qv, kv, vv);
  k_final<<<4, 128, 0, stream>>>(HC, glob, qv, kv, vv, mwT, map_b, gamma, alpha, out);
}